// Round 5
// baseline (131.653 us; speedup 1.0000x reference)
//
#include <hip/hip_runtime.h>
#include <hip/hip_bf16.h>

// Problem dims
#define B_    2
#define CIN   128
#define COUT  128
#define DD    16
#define HH    32
#define WW    32
#define XS_CI (DD*HH*WW)       // 16384
#define XS_B  (CIN*XS_CI)
// out strides: [b][co][d2][h2][w2]
#define OS_H2 64
#define OS_D2 (64*64)
#define OS_CO (32*64*64)
#define OS_B  (COUT*OS_CO)

// padded bf16 x: [b][ci][18][34][36], interior at d:1..16, h:1..32, w:2..33
#define PD_D  18
#define PD_H  34
#define PD_W  36
#define PD_HW (PD_H*PD_W)      // 1224
#define PD_CI (PD_D*PD_HW)     // 22032
#define AFOLD_BYTES (8*32*8*64*16)          // 2 MiB
#define XPAD_ELEMS  ((size_t)B_*CIN*PD_CI)
#define XPAD_BYTES  (XPAD_ELEMS*2)

typedef __attribute__((ext_vector_type(8))) short        short8;
typedef __attribute__((ext_vector_type(4))) float        floatx4;
typedef __attribute__((ext_vector_type(4))) unsigned int uint4v;

static __device__ __forceinline__ unsigned f2bf(float f) {
    union { __hip_bfloat16 h; unsigned short u; } cv;
    cv.h = __float2bfloat16(f);
    return (unsigned)cv.u;
}

// ---------------------------------------------------------------------------
// Kernel 1: fold 3x3x3 weights into per-parity 2x2x2 effective kernels,
// bf16, MFMA A-fragment order (verified rounds 2-4).
// ---------------------------------------------------------------------------
__global__ __launch_bounds__(256) void fold_kernel(const float* __restrict__ Wk,
                                                   unsigned short* __restrict__ Afold) {
    const int t = blockIdx.x * 256 + threadIdx.x;   // 0 .. 131071
    const int p  = t >> 14;
    const int ks = (t >> 9) & 31;
    const int ct = (t >> 6) & 7;
    const int l  = t & 63;
    const int co = ct * 16 + (l & 15);
    const int ci = ks * 4 + (l >> 4);
    const int ed = (p >> 2) & 1, eh = (p >> 1) & 1, ew = p & 1;

    const float* w = Wk + (co * CIN + ci) * 27;
    float wv[27];
    #pragma unroll
    for (int i = 0; i < 27; ++i) wv[i] = w[i];

    short8 pk;
    #pragma unroll
    for (int tt = 0; tt < 8; ++tt) {
        const int td = (tt >> 2) & 1, th = (tt >> 1) & 1, tw = tt & 1;
        const int dlo = ed ? (td ? 2 : 0) : (td ? 1 : 0);
        const int dhi = ed ? (td ? 2 : 1) : (td ? 2 : 0);
        const int hlo = eh ? (th ? 2 : 0) : (th ? 1 : 0);
        const int hhi = eh ? (th ? 2 : 1) : (th ? 2 : 0);
        const int wlo = ew ? (tw ? 2 : 0) : (tw ? 1 : 0);
        const int whi = ew ? (tw ? 2 : 1) : (tw ? 2 : 0);
        float s = 0.f;
        for (int kd = dlo; kd <= dhi; ++kd)
            for (int kh = hlo; kh <= hhi; ++kh)
                for (int kw = wlo; kw <= whi; ++kw)
                    s += wv[kd * 9 + kh * 3 + kw];
        pk[tt] = (short)f2bf(s);
    }
    reinterpret_cast<short8*>(Afold)[t] = pk;
}

// ---------------------------------------------------------------------------
// Kernel 2: convert+pad x into bf16 [b][ci][18][34][36] (borders pre-zeroed
// by hipMemsetAsync). One thread per w-pair; aligned u32 stores.
// ---------------------------------------------------------------------------
__global__ __launch_bounds__(256) void pad_kernel(const float* __restrict__ x,
                                                  unsigned* __restrict__ xp32) {
    const int idx = blockIdx.x * 256 + threadIdx.x;   // 0 .. 2,097,151
    const int w2 = idx & 15;
    const int h  = (idx >> 4) & 31;
    const int d  = (idx >> 9) & 15;
    const int ci = (idx >> 13) & 127;
    const int b  = (idx >> 20) & 1;
    const float2 v = *reinterpret_cast<const float2*>(
        x + (size_t)((b * CIN + ci) * DD + d) * (HH * WW) + h * WW + w2 * 2);
    xp32[(size_t)((b * CIN + ci) * PD_D + d + 1) * (PD_HW / 2)
         + (h + 1) * (PD_W / 2) + (w2 + 1)] = f2bf(v.x) | (f2bf(v.y) << 16);
}

// ---------------------------------------------------------------------------
// Kernel 3: per-parity implicit GEMM, software-pipelined.
//   Changes vs r4: (1) LDS swizzle key ((n>>1)&7) -> conflict-free writes AND
//   reads; (2) depth-2 gather prefetch (two register buffers, gather kc+2
//   issued at body kc) to cover HBM latency.
// ---------------------------------------------------------------------------
__global__ __launch_bounds__(256, 3) void upconv_mfma(
    const unsigned short* __restrict__ xp,
    const unsigned short* __restrict__ Afold,
    const float* __restrict__ bias,
    float* __restrict__ out)
{
    __shared__ short Bt[2][128 * 64];   // 2 x 16 KiB
    char* buf0 = reinterpret_cast<char*>(&Bt[0][0]);
    char* buf1 = reinterpret_cast<char*>(&Bt[1][0]);

    const int tid  = threadIdx.x;
    const int wave = tid >> 6;
    const int lane = tid & 63;

    const int d      = blockIdx.x >> 3;
    const int h_base = (blockIdx.x & 7) * 4;
    const int p      = blockIdx.y;
    const int b      = blockIdx.z;
    const int ed = (p >> 2) & 1, eh = (p >> 1) & 1, ew = p & 1;

    // ---- staging geometry (chunk-invariant) ----
    const int npair = tid & 63;
    const int grp   = tid >> 6;                 // ci group 0..3
    const int hl    = npair >> 4;               // 0..3
    const int wlp   = (npair & 15) * 2;         // 0,2,..,30
    const int n_a   = hl * 32 + wlp;
    const int n_b   = n_a + 1;
    const int pd  = d + ed;
    const int ph  = h_base + hl + eh;
    const int pwb = wlp + 2 * ew;               // aligned base elem (even)
    const int roff = pd * PD_HW + ph * PD_W + pwb;
    const unsigned short* xpb = xp + (size_t)b * CIN * PD_CI;

    int waddr_a[2], waddr_b[2];
    #pragma unroll
    for (int i = 0; i < 2; ++i) {
        const int cl = grp * 2 + i;             // ci_loc within chunk
        waddr_a[i] = n_a * 128 + ((cl * 16) ^ (((n_a >> 1) & 7) << 4));
        waddr_b[i] = n_b * 128 + ((cl * 16) ^ (((n_b >> 1) & 7) << 4));
    }

    // ---- MFMA-read geometry (chunk-invariant) ----
    const int co0 = (wave >> 1) * 64;
    const int n0  = (wave & 1) * 64;
    const int ct0 = (wave >> 1) * 4;
    int raddr[2][4];
    #pragma unroll
    for (int ksl = 0; ksl < 2; ++ksl)
        #pragma unroll
        for (int nt = 0; nt < 4; ++nt) {
            const int n  = n0 + nt * 16 + (lane & 15);
            const int kb = ksl * 64 + (lane >> 4) * 16;
            raddr[ksl][nt] = n * 128 + (kb ^ (((n >> 1) & 7) << 4));
        }

    floatx4 acc[4][4];
    #pragma unroll
    for (int i = 0; i < 4; ++i)
        #pragma unroll
        for (int j = 0; j < 4; ++j)
            acc[i][j] = (floatx4){0.f, 0.f, 0.f, 0.f};

    const short8* Ap = reinterpret_cast<const short8*>(Afold);

    unsigned gA[2][4][2], gB[2][4][2];   // two prefetch buffers (depth-2)

    #define GATHER(gbuf, kc)                                                    \
        do {                                                                    \
            _Pragma("unroll")                                                   \
            for (int i = 0; i < 2; ++i) {                                       \
                const char* bc = reinterpret_cast<const char*>(                 \
                    xpb + (size_t)((kc) * 8 + grp * 2 + i) * PD_CI + roff);     \
                gbuf[i][0][0] = *(const unsigned*)(bc + 0);                     \
                gbuf[i][0][1] = *(const unsigned*)(bc + 4);                     \
                gbuf[i][1][0] = *(const unsigned*)(bc + 72);                    \
                gbuf[i][1][1] = *(const unsigned*)(bc + 76);                    \
                gbuf[i][2][0] = *(const unsigned*)(bc + 2448);                  \
                gbuf[i][2][1] = *(const unsigned*)(bc + 2452);                  \
                gbuf[i][3][0] = *(const unsigned*)(bc + 2520);                  \
                gbuf[i][3][1] = *(const unsigned*)(bc + 2524);                  \
            }                                                                   \
        } while (0)

    #define BODY(kc, bufc, g, dofill)                                           \
        do {                                                                    \
            /* 1) A-fragment loads first (L2-resident) */                       \
            short8 a[2][4];                                                     \
            _Pragma("unroll")                                                   \
            for (int ksl = 0; ksl < 2; ++ksl)                                   \
                _Pragma("unroll")                                               \
                for (int ct = 0; ct < 4; ++ct)                                  \
                    a[ksl][ct] = Ap[(size_t)(((p) * 32 + (kc) * 2 + ksl) * 8    \
                                             + ct0 + ct) * 64 + lane];          \
            /* 2) extract tap-pairs from gathered chunk kc, write LDS */        \
            _Pragma("unroll")                                                   \
            for (int i = 0; i < 2; ++i) {                                       \
                unsigned pa[4], pb[4];                                          \
                _Pragma("unroll")                                               \
                for (int r = 0; r < 4; ++r) {                                   \
                    const unsigned l0 = g[i][r][0], l1 = g[i][r][1];            \
                    const unsigned mid = (l0 >> 16) | (l1 << 16);               \
                    pa[r] = ew ? l0  : mid;                                     \
                    pb[r] = ew ? mid : l1;                                      \
                }                                                               \
                *(uint4v*)(bufc + waddr_a[i]) = (uint4v){pa[0],pa[1],pa[2],pa[3]}; \
                *(uint4v*)(bufc + waddr_b[i]) = (uint4v){pb[0],pb[1],pb[2],pb[3]}; \
            }                                                                   \
            /* 3) refill this buffer with chunk kc+2 (in flight ~2 chunks) */   \
            if (dofill) GATHER(g, (kc) + 2);                                    \
            /* 4) LDS-visibility-only barrier (do NOT drain vmcnt) */           \
            asm volatile("s_waitcnt lgkmcnt(0)\n\ts_barrier" ::: "memory");     \
            /* 5) MFMA */                                                       \
            __builtin_amdgcn_s_setprio(1);                                      \
            _Pragma("unroll")                                                   \
            for (int ksl = 0; ksl < 2; ++ksl) {                                 \
                short8 bfr[4];                                                  \
                _Pragma("unroll")                                               \
                for (int nt = 0; nt < 4; ++nt)                                  \
                    bfr[nt] = *reinterpret_cast<const short8*>(                 \
                        bufc + raddr[ksl][nt]);                                 \
                _Pragma("unroll")                                               \
                for (int ct = 0; ct < 4; ++ct)                                  \
                    _Pragma("unroll")                                           \
                    for (int nt = 0; nt < 4; ++nt)                              \
                        acc[ct][nt] = __builtin_amdgcn_mfma_f32_16x16x32_bf16(  \
                            a[ksl][ct], bfr[nt], acc[ct][nt], 0, 0, 0);         \
            }                                                                   \
            __builtin_amdgcn_s_setprio(0);                                      \
        } while (0)

    GATHER(gA, 0);
    GATHER(gB, 1);
    for (int kc = 0; kc < 16; kc += 2) {
        BODY(kc,     buf0, gA, kc + 2 < 16);
        BODY(kc + 1, buf1, gB, kc + 3 < 16);
    }
    #undef BODY
    #undef GATHER

    // ---- epilogue: add bias, scatter to upsampled layout ----
    float* ob = out + (size_t)b * OS_B + (size_t)(2 * d + ed) * OS_D2;
    #pragma unroll
    for (int ct = 0; ct < 4; ++ct) {
        #pragma unroll
        for (int j = 0; j < 4; ++j) {
            const int co = co0 + ct * 16 + (lane >> 4) * 4 + j;
            const float bv = bias[co];
            #pragma unroll
            for (int nt = 0; nt < 4; ++nt) {
                const int n  = n0 + nt * 16 + (lane & 15);
                const int hh = n >> 5, wl = n & 31;
                const int h2 = 2 * (h_base + hh) + eh;
                const int w2 = 2 * wl + ew;
                ob[(size_t)co * OS_CO + h2 * OS_H2 + w2] = acc[ct][nt][j] + bv;
            }
        }
    }
}

extern "C" void kernel_launch(void* const* d_in, const int* in_sizes, int n_in,
                              void* d_out, int out_size, void* d_ws, size_t ws_size,
                              hipStream_t stream) {
    const float* x    = (const float*)d_in[0];
    const float* Wk   = (const float*)d_in[1];
    const float* bias = (const float*)d_in[2];
    float* out        = (float*)d_out;

    unsigned short* Afold = (unsigned short*)d_ws;
    unsigned short* xpad  = (unsigned short*)((char*)d_ws + AFOLD_BYTES);

    hipMemsetAsync(xpad, 0, XPAD_BYTES, stream);
    pad_kernel<<<8192, 256, 0, stream>>>(x, (unsigned*)xpad);
    fold_kernel<<<512, 256, 0, stream>>>(Wk, Afold);

    dim3 grid(DD * 8, 8, B_);   // (128, 8 parity, 2 batch)
    upconv_mfma<<<grid, 256, 0, stream>>>(xpad, Afold, bias, out);
}